// Round 6
// baseline (794.487 us; speedup 1.0000x reference)
//
#include <hip/hip_runtime.h>
#include <hip/hip_fp16.h>
#include <cstdint>

typedef _Float16 half8  __attribute__((ext_vector_type(8)));
typedef _Float16 half4v __attribute__((ext_vector_type(4)));
typedef float    floatx4 __attribute__((ext_vector_type(4)));

// problem dims (fixed by setup_inputs)
constexpr int Bb = 4, Ss = 4096, Dd = 1024;
constexpr int Mdim = Bb * Ss;          // 16384
constexpr int Ndim = 3 * Dd;           // 3072
constexpr int Kdim = Dd;               // 1024
constexpr int CH = 128, LCH = 32, HLCH = 16;  // 128 chunks of 32 steps, 2 halves

// ---------------------------------------------------------------- utils
__device__ __forceinline__ void gload_lds16(const void* g, void* l) {
  __builtin_amdgcn_global_load_lds(
      (const __attribute__((address_space(1))) uint32_t*)g,
      (__attribute__((address_space(3))) uint32_t*)l, 16, 0, 0);
}

// gate math: fw = sig(f)/(sig(f)+sig(i)) = (1+e^-i)/(2+e^-f+e^-i)
//            iw = (1+e^-f)/(2+e^-f+e^-i);  v = iw * g~(h)
__device__ __forceinline__ void gate_fv(float fg, float ig, float hg,
                                        float& fw, float& v) {
  float ef = __expf(fminf(-fg, 40.f));
  float ei = __expf(fminf(-ig, 40.f));
  float r  = __builtin_amdgcn_rcpf(2.f + ef + ei);
  fw = (1.f + ei) * r;
  float iw = (1.f + ef) * r;
  float g  = hg >= 0.f ? hg + 0.5f
                       : __builtin_amdgcn_rcpf(1.f + __expf(fminf(-hg, 40.f)));
  v = iw * g;
}

// ---------------------------------------------------------------- K0a: x fp32 -> fp16
__global__ __launch_bounds__(256) void cvt_x_k(const float* __restrict__ X,
                                               _Float16* __restrict__ X16, int n4) {
  for (int i = blockIdx.x * blockDim.x + threadIdx.x; i < n4;
       i += gridDim.x * blockDim.x) {
    float4 v = ((const float4*)X)[i];
    half4v o = {(_Float16)v.x, (_Float16)v.y, (_Float16)v.z, (_Float16)v.w};
    ((half4v*)X16)[i] = o;
  }
}

// ---------------------------------------------------------------- K0b: W [K][N] fp32 -> WT [N][K] fp16
__global__ __launch_bounds__(256) void cvt_wT_k(const float* __restrict__ W,
                                                _Float16* __restrict__ WT) {
  __shared__ float tile[32][33];
  int tx = threadIdx.x & 31, ty = threadIdx.x >> 5;  // 32 x 8
  int n0 = blockIdx.x * 32, k0 = blockIdx.y * 32;
#pragma unroll
  for (int j = 0; j < 4; ++j) {
    int k = ty + j * 8;
    tile[k][tx] = W[(int64_t)(k0 + k) * Ndim + n0 + tx];
  }
  __syncthreads();
#pragma unroll
  for (int j = 0; j < 4; ++j) {
    int nl = ty + j * 8;
    WT[(int64_t)(n0 + nl) * Kdim + k0 + tx] = (_Float16)tile[tx][nl];
  }
}

// ---------------------------------------------------------------- K1: 256x256 GEMM, deep-prefetch 2-barrier/tile
// (unchanged from round 4 — 102 us, MfmaUtil ~44%)
constexpr int GBM = 256, GBN = 256, GBK = 64;
constexpr int NT = Kdim / GBK;  // 16 K-tiles

__global__ __launch_bounds__(512, 2) void gemm8_k(const _Float16* __restrict__ A,
                                                  const _Float16* __restrict__ BT,
                                                  _Float16* __restrict__ Cg) {
  extern __shared__ char lds[];  // 131072 bytes
  const int tid = threadIdx.x;
  const int wid = tid >> 6, lane = tid & 63;
  const int wm = wid >> 2, wn = wid & 3;
  const int l15 = lane & 15, lq = lane >> 4;

  // XCD-aware swizzle (768 % 8 == 0 -> simple variant is bijective)
  int wg = blockIdx.x;
  wg = (wg & 7) * 96 + (wg >> 3);
  const int n0 = (wg % 12) * GBN;
  const int m0 = (wg / 12) * GBM;

  int aO[4], bO[2];
#pragma unroll
  for (int mi = 0; mi < 4; ++mi) {
    int r = wm * 64 + mi * 16 + l15;
    aO[mi] = r * 128 + ((lq ^ (r & 7)) << 4);
  }
#pragma unroll
  for (int ni = 0; ni < 2; ++ni) {
    int r = wn * 32 + ni * 16 + l15;
    bO[ni] = r * 128 + ((lq ^ (r & 7)) << 4);
  }

  const int srr = (wid << 3) + (lane >> 3);
  const int ss = lane & 7;
  const _Float16* Abase = A + (size_t)m0 * Kdim;
  const _Float16* Bbase = BT + (size_t)n0 * Kdim;

  auto stage = [&](const _Float16* gsrc, int ldsHalfBase) {
#pragma unroll
    for (int round = 0; round < 2; ++round) {
      int r = (round << 6) + srr;
      int c = ss ^ (r & 7);
      gload_lds16(gsrc + (size_t)r * Kdim + (c << 3),
                  lds + ldsHalfBase + (round << 13) + (wid << 10));
    }
  };

  floatx4 acc[8][4] = {};

  stage(Abase, 0);                          // A0(0)
  stage(Bbase, 32768);                      // B0(0)
  stage(Bbase + 128 * Kdim, 49152);         // B1(0)
  stage(Abase + 128 * Kdim, 16384);         // A1(0)
  stage(Abase + 64, 65536);                 // A0(1)
  stage(Bbase + 64, 65536 + 32768);         // B0(1)
  asm volatile("s_waitcnt vmcnt(4)" ::: "memory");
  __builtin_amdgcn_s_barrier();

  for (int kt = 0; kt < NT; ++kt) {
    const int cur = (kt & 1) << 16, nxt = ((kt + 1) & 1) << 16;
    const _Float16* Akt1 = Abase + (kt + 1) * GBK;
    const _Float16* Bkt1 = Bbase + (kt + 1) * GBK;
    const _Float16* Akt2 = Abase + (kt + 2) * GBK;
    const _Float16* Bkt2 = Bbase + (kt + 2) * GBK;

    half8 a[4][2], b0[2][2], b1[2][2];

#pragma unroll
    for (int mi = 0; mi < 4; ++mi)
#pragma unroll
      for (int ks = 0; ks < 2; ++ks)
        a[mi][ks] = *(const half8*)(lds + cur + (aO[mi] ^ (ks << 6)));
#pragma unroll
    for (int ni = 0; ni < 2; ++ni)
#pragma unroll
      for (int ks = 0; ks < 2; ++ks) {
        b0[ni][ks] = *(const half8*)(lds + cur + 32768 + (bO[ni] ^ (ks << 6)));
        b1[ni][ks] = *(const half8*)(lds + cur + 49152 + (bO[ni] ^ (ks << 6)));
      }
    if (kt + 1 < NT) stage(Bkt1 + 128 * Kdim, nxt + 49152);  // s0: B1(kt+1)

    __builtin_amdgcn_s_setprio(1);
#pragma unroll
    for (int ks = 0; ks < 2; ++ks)
#pragma unroll
      for (int mi = 0; mi < 4; ++mi)
#pragma unroll
        for (int ni = 0; ni < 2; ++ni)
          acc[mi][ni] = __builtin_amdgcn_mfma_f32_16x16x32_f16(
              a[mi][ks], b0[ni][ks], acc[mi][ni], 0, 0, 0);
    __builtin_amdgcn_s_setprio(0);
    if (kt + 1 < NT) stage(Akt1 + 128 * Kdim, nxt + 16384);  // s1: A1(kt+1)

    __builtin_amdgcn_s_setprio(1);
#pragma unroll
    for (int ks = 0; ks < 2; ++ks)
#pragma unroll
      for (int mi = 0; mi < 4; ++mi)
#pragma unroll
        for (int ni = 0; ni < 2; ++ni)
          acc[mi][2 + ni] = __builtin_amdgcn_mfma_f32_16x16x32_f16(
              a[mi][ks], b1[ni][ks], acc[mi][2 + ni], 0, 0, 0);
    __builtin_amdgcn_s_setprio(0);

    __builtin_amdgcn_s_barrier();

#pragma unroll
    for (int mi = 0; mi < 4; ++mi)
#pragma unroll
      for (int ks = 0; ks < 2; ++ks)
        a[mi][ks] = *(const half8*)(lds + cur + 16384 + (aO[mi] ^ (ks << 6)));
    if (kt + 2 < NT) stage(Akt2, cur + 0);  // s2: A0(kt+2)

    __builtin_amdgcn_s_setprio(1);
#pragma unroll
    for (int ks = 0; ks < 2; ++ks)
#pragma unroll
      for (int mi = 0; mi < 4; ++mi)
#pragma unroll
        for (int ni = 0; ni < 2; ++ni)
          acc[4 + mi][ni] = __builtin_amdgcn_mfma_f32_16x16x32_f16(
              a[mi][ks], b0[ni][ks], acc[4 + mi][ni], 0, 0, 0);
    __builtin_amdgcn_s_setprio(0);
    if (kt + 2 < NT) stage(Bkt2, cur + 32768);  // s3: B0(kt+2)

    __builtin_amdgcn_s_setprio(1);
#pragma unroll
    for (int ks = 0; ks < 2; ++ks)
#pragma unroll
      for (int mi = 0; mi < 4; ++mi)
#pragma unroll
        for (int ni = 0; ni < 2; ++ni)
          acc[4 + mi][2 + ni] = __builtin_amdgcn_mfma_f32_16x16x32_f16(
              a[mi][ks], b1[ni][ks], acc[4 + mi][2 + ni], 0, 0, 0);
    __builtin_amdgcn_s_setprio(0);

    if (kt < NT - 2) {
      asm volatile("s_waitcnt vmcnt(4)" ::: "memory");
      __builtin_amdgcn_s_barrier();
    } else if (kt == NT - 2) {
      asm volatile("s_waitcnt vmcnt(0)" ::: "memory");
      __builtin_amdgcn_s_barrier();
    }
  }

#pragma unroll
  for (int mf = 0; mf < 8; ++mf) {
    int row = m0 + ((mf >> 2) << 7) + wm * 64 + ((mf & 3) << 4) + (lq << 2);
#pragma unroll
    for (int nf = 0; nf < 4; ++nf) {
      int col = n0 + ((nf >> 1) << 7) + wn * 32 + ((nf & 1) << 4) + l15;
#pragma unroll
      for (int r = 0; r < 4; ++r)
        Cg[(size_t)(row + r) * Ndim + col] = (_Float16)acc[mf][nf][r];
    }
  }
}

// ---------------------------------------------------------------- K2: single-pass scan, decoupled lookback
// Each block: one (b, chunk) of 32 steps x 1024 channels. 512 threads:
// half = tid>>8 (step-halves 0..15 / 16..31), dg = tid&255 (4 d-channels).
// LDS caches rounded (f,v) fp16 so gates are read exactly once.
// Aggregate semantics: segment maps h -> F*h + H. flags: 0 none, 1 agg, 2 inclusive.
__global__ __launch_bounds__(512) void scanF_k(const _Float16* __restrict__ G,
                                               float* __restrict__ Fc,
                                               float* __restrict__ Hc,
                                               float* __restrict__ Vc,
                                               unsigned* __restrict__ flags,
                                               unsigned* __restrict__ ticket,
                                               float* __restrict__ Out) {
  extern __shared__ char smem[];
  _Float16* f_lds = (_Float16*)smem;             // [32][1024] = 64 KiB
  _Float16* v_lds = (_Float16*)(smem + 65536);   // [32][1024] = 64 KiB
  float* comb = (float*)(smem + 131072);         // [256][8]   = 8 KiB
  __shared__ unsigned sIdx;

  const int tid = threadIdx.x;
  if (tid == 0) sIdx = atomicAdd(ticket, 1u);
  __syncthreads();
  const unsigned idx = sIdx;
  const int b = idx & 3, c = idx >> 2;  // chunks ascend with ticket -> no deadlock
  const int half = tid >> 8, dg = tid & 255;
  const int d = dg * 4;
  const int fi = b * CH + c;
  const int co = fi * Dd + d;

  // ---- phase 1: local scan of this half (16 steps), cache rounded f,v in LDS
  const _Float16* g = G + (int64_t)(b * Ss + c * LCH + half * HLCH) * Ndim + d;
  float F[4] = {1.f, 1.f, 1.f, 1.f}, H[4] = {0.f, 0.f, 0.f, 0.f};
  for (int s = 0; s < HLCH; ++s) {
    int sl = half * HLCH + s;
    half4v fg = *(const half4v*)(g);
    half4v ig = *(const half4v*)(g + Dd);
    half4v hg = *(const half4v*)(g + 2 * Dd);
    half4v fo, vo;
#pragma unroll
    for (int j = 0; j < 4; ++j) {
      float fw, v;
      gate_fv((float)fg[j], (float)ig[j], (float)hg[j], fw, v);
      fo[j] = (_Float16)fw;
      vo[j] = (_Float16)v;
      float fr = (float)fo[j], vr = (float)vo[j];  // rounded, consistent w/ replay
      H[j] = fmaf(fr, H[j], vr);
      F[j] *= fr;
    }
    *(half4v*)(f_lds + sl * 1024 + d) = fo;
    *(half4v*)(v_lds + sl * 1024 + d) = vo;
    g += Ndim;
  }
  if (half == 0) {
    *(floatx4*)(comb + dg * 8)     = *(floatx4*)F;
    *(floatx4*)(comb + dg * 8 + 4) = *(floatx4*)H;
  }
  __syncthreads();

  // ---- chunk aggregate (half B composes A-then-B), publish flag=1
  float Fa[4], Ha[4], Fg_[4], Hg_[4];
  {
    floatx4 fa = *(const floatx4*)(comb + dg * 8);
    floatx4 ha = *(const floatx4*)(comb + dg * 8 + 4);
#pragma unroll
    for (int j = 0; j < 4; ++j) { Fa[j] = fa[j]; Ha[j] = ha[j]; }
  }
  if (half == 1) {
#pragma unroll
    for (int j = 0; j < 4; ++j) {
      Fg_[j] = Fa[j] * F[j];
      Hg_[j] = fmaf(F[j], Ha[j], H[j]);
    }
    *(floatx4*)(Fc + co) = *(floatx4*)Fg_;
    *(floatx4*)(Hc + co) = *(floatx4*)Hg_;
  }
  __threadfence();
  __syncthreads();
  if (tid == 256)
    __hip_atomic_store(&flags[fi], 1u, __ATOMIC_RELEASE, __HIP_MEMORY_SCOPE_AGENT);

  // ---- lookback (per-thread; acquire-load flag orders each thread's data loads)
  float carry[4] = {0.f, 0.f, 0.f, 0.f};
  if (c > 0) {
    float Fw[4] = {1.f, 1.f, 1.f, 1.f}, Hw[4] = {0.f, 0.f, 0.f, 0.f};
    int p = c - 1;
    for (;;) {
      unsigned fl;
      for (;;) {
        fl = __hip_atomic_load(&flags[b * CH + p], __ATOMIC_ACQUIRE,
                               __HIP_MEMORY_SCOPE_AGENT);
        if (fl) break;
        __builtin_amdgcn_s_sleep(8);
      }
      int po = (b * CH + p) * Dd + d;
      if (fl == 2u) {
        floatx4 vp = *(const floatx4*)(Vc + po);
#pragma unroll
        for (int j = 0; j < 4; ++j) carry[j] = fmaf(Fw[j], vp[j], Hw[j]);
        break;
      } else {
        floatx4 fp = *(const floatx4*)(Fc + po);
        floatx4 hp = *(const floatx4*)(Hc + po);
#pragma unroll
        for (int j = 0; j < 4; ++j) {
          Hw[j] = fmaf(Fw[j], hp[j], Hw[j]);
          Fw[j] *= fp[j];
        }
        if (--p < 0) {
#pragma unroll
          for (int j = 0; j < 4; ++j) carry[j] = Hw[j];
          break;
        }
      }
    }
  }

  // ---- publish inclusive value, flag=2
  if (half == 1) {
    float vi[4];
#pragma unroll
    for (int j = 0; j < 4; ++j) vi[j] = fmaf(Fg_[j], carry[j], Hg_[j]);
    *(floatx4*)(Vc + co) = *(floatx4*)vi;
  }
  __threadfence();
  __syncthreads();
  if (tid == 256)
    __hip_atomic_store(&flags[fi], 2u, __ATOMIC_RELEASE, __HIP_MEMORY_SCOPE_AGENT);

  // ---- phase 3: replay from LDS with correct carry-in, write fp32 out
  float h[4];
#pragma unroll
  for (int j = 0; j < 4; ++j)
    h[j] = (half == 0) ? carry[j] : fmaf(Fa[j], carry[j], Ha[j]);
  float* o = Out + (int64_t)(b * Ss + c * LCH + half * HLCH) * Dd + d;
  for (int s = 0; s < HLCH; ++s) {
    int sl = half * HLCH + s;
    half4v fo = *(const half4v*)(f_lds + sl * 1024 + d);
    half4v vo = *(const half4v*)(v_lds + sl * 1024 + d);
#pragma unroll
    for (int j = 0; j < 4; ++j) h[j] = fmaf((float)fo[j], h[j], (float)vo[j]);
    *(floatx4*)o = *(floatx4*)h;
    o += Dd;
  }
}

// ---------------------------------------------------------------- launch
extern "C" void kernel_launch(void* const* d_in, const int* in_sizes, int n_in,
                              void* d_out, int out_size, void* d_ws, size_t ws_size,
                              hipStream_t stream) {
  const float* x = (const float*)d_in[0];   // [B,S,D] fp32
  const float* W = (const float*)d_in[1];   // [D,3D] fp32
  float* out = (float*)d_out;               // [B,S,D] fp32

  char* ws = (char*)d_ws;
  size_t off = 0;
  auto alloc = [&](size_t bytes) {
    char* p = ws + off;
    off += (bytes + 255) & ~size_t(255);
    return p;
  };
  _Float16* x16    = (_Float16*)alloc((size_t)Mdim * Kdim * 2);       // 32 MiB
  _Float16* w16t   = (_Float16*)alloc((size_t)Ndim * Kdim * 2);       // 6 MiB
  _Float16* gates  = (_Float16*)alloc((size_t)Mdim * Ndim * 2);       // 96 MiB
  float* Fc        = (float*)alloc((size_t)Bb * CH * Dd * 4);         // 2 MiB
  float* Hc        = (float*)alloc((size_t)Bb * CH * Dd * 4);
  float* Vc        = (float*)alloc((size_t)Bb * CH * Dd * 4);
  unsigned* flags  = (unsigned*)alloc((Bb * CH + 1) * 4);             // flags + ticket
  unsigned* ticket = flags + Bb * CH;
  if (off > ws_size) return;  // workspace too small: fail cleanly

  hipMemsetAsync(flags, 0, (Bb * CH + 1) * sizeof(unsigned), stream);
  cvt_x_k<<<2048, 256, 0, stream>>>(x, x16, Mdim * Kdim / 4);
  cvt_wT_k<<<dim3(Ndim / 32, Kdim / 32), 256, 0, stream>>>(W, w16t);
  gemm8_k<<<dim3((Mdim / GBM) * (Ndim / GBN)), 512, 131072, stream>>>(x16, w16t, gates);
  scanF_k<<<Bb * CH, 512, 139264, stream>>>(gates, Fc, Hc, Vc, flags, ticket, out);
}

// Round 7
// 197.146 us; speedup vs baseline: 4.0299x; 4.0299x over previous
//
#include <hip/hip_runtime.h>
#include <hip/hip_fp16.h>
#include <cstdint>

typedef _Float16 half8  __attribute__((ext_vector_type(8)));
typedef _Float16 half4v __attribute__((ext_vector_type(4)));
typedef float    floatx4 __attribute__((ext_vector_type(4)));

// problem dims (fixed by setup_inputs)
constexpr int Bb = 4, Ss = 4096, Dd = 1024;
constexpr int Mdim = Bb * Ss;          // 16384
constexpr int Ndim = 3 * Dd;           // 3072
constexpr int Kdim = Dd;               // 1024
constexpr int CH = 256, LCH = Ss / CH; // 256 chunks of 16 steps

// ---------------------------------------------------------------- utils
__device__ __forceinline__ void gload_lds16(const void* g, void* l) {
  __builtin_amdgcn_global_load_lds(
      (const __attribute__((address_space(1))) uint32_t*)g,
      (__attribute__((address_space(3))) uint32_t*)l, 16, 0, 0);
}

// gate math: fw = sig(f)/(sig(f)+sig(i)) = (1+e^-i)/(2+e^-f+e^-i)
//            iw = (1+e^-f)/(2+e^-f+e^-i);  v = iw * g~(h)
__device__ __forceinline__ void gate_fv(float fg, float ig, float hg,
                                        float& fw, float& v) {
  float ef = __expf(fminf(-fg, 40.f));
  float ei = __expf(fminf(-ig, 40.f));
  float r  = __builtin_amdgcn_rcpf(2.f + ef + ei);
  fw = (1.f + ei) * r;
  float iw = (1.f + ef) * r;
  float g  = hg >= 0.f ? hg + 0.5f
                       : __builtin_amdgcn_rcpf(1.f + __expf(fminf(-hg, 40.f)));
  v = iw * g;
}

// ---------------------------------------------------------------- K0a: x fp32 -> fp16
__global__ __launch_bounds__(256) void cvt_x_k(const float* __restrict__ X,
                                               _Float16* __restrict__ X16, int n4) {
  for (int i = blockIdx.x * blockDim.x + threadIdx.x; i < n4;
       i += gridDim.x * blockDim.x) {
    float4 v = ((const float4*)X)[i];
    half4v o = {(_Float16)v.x, (_Float16)v.y, (_Float16)v.z, (_Float16)v.w};
    ((half4v*)X16)[i] = o;
  }
}

// ---------------------------------------------------------------- K0b: W [K][N] fp32 -> WT [N][K] fp16
__global__ __launch_bounds__(256) void cvt_wT_k(const float* __restrict__ W,
                                                _Float16* __restrict__ WT) {
  __shared__ float tile[32][33];
  int tx = threadIdx.x & 31, ty = threadIdx.x >> 5;  // 32 x 8
  int n0 = blockIdx.x * 32, k0 = blockIdx.y * 32;
#pragma unroll
  for (int j = 0; j < 4; ++j) {
    int k = ty + j * 8;
    tile[k][tx] = W[(int64_t)(k0 + k) * Ndim + n0 + tx];
  }
  __syncthreads();
#pragma unroll
  for (int j = 0; j < 4; ++j) {
    int nl = ty + j * 8;
    WT[(int64_t)(n0 + nl) * Kdim + k0 + tx] = (_Float16)tile[tx][nl];
  }
}

// ---------------------------------------------------------------- K1: 256x256 GEMM, deep-prefetch 2-barrier/tile
// (frozen since round 4 — 102 us, MfmaUtil ~44%)
constexpr int GBM = 256, GBN = 256, GBK = 64;
constexpr int NT = Kdim / GBK;  // 16 K-tiles

__global__ __launch_bounds__(512, 2) void gemm8_k(const _Float16* __restrict__ A,
                                                  const _Float16* __restrict__ BT,
                                                  _Float16* __restrict__ Cg) {
  extern __shared__ char lds[];  // 131072 bytes
  const int tid = threadIdx.x;
  const int wid = tid >> 6, lane = tid & 63;
  const int wm = wid >> 2, wn = wid & 3;
  const int l15 = lane & 15, lq = lane >> 4;

  // XCD-aware swizzle (768 % 8 == 0 -> simple variant is bijective)
  int wg = blockIdx.x;
  wg = (wg & 7) * 96 + (wg >> 3);
  const int n0 = (wg % 12) * GBN;
  const int m0 = (wg / 12) * GBM;

  int aO[4], bO[2];
#pragma unroll
  for (int mi = 0; mi < 4; ++mi) {
    int r = wm * 64 + mi * 16 + l15;
    aO[mi] = r * 128 + ((lq ^ (r & 7)) << 4);
  }
#pragma unroll
  for (int ni = 0; ni < 2; ++ni) {
    int r = wn * 32 + ni * 16 + l15;
    bO[ni] = r * 128 + ((lq ^ (r & 7)) << 4);
  }

  const int srr = (wid << 3) + (lane >> 3);
  const int ss = lane & 7;
  const _Float16* Abase = A + (size_t)m0 * Kdim;
  const _Float16* Bbase = BT + (size_t)n0 * Kdim;

  auto stage = [&](const _Float16* gsrc, int ldsHalfBase) {
#pragma unroll
    for (int round = 0; round < 2; ++round) {
      int r = (round << 6) + srr;
      int c = ss ^ (r & 7);
      gload_lds16(gsrc + (size_t)r * Kdim + (c << 3),
                  lds + ldsHalfBase + (round << 13) + (wid << 10));
    }
  };

  floatx4 acc[8][4] = {};

  stage(Abase, 0);                          // A0(0)
  stage(Bbase, 32768);                      // B0(0)
  stage(Bbase + 128 * Kdim, 49152);         // B1(0)
  stage(Abase + 128 * Kdim, 16384);         // A1(0)
  stage(Abase + 64, 65536);                 // A0(1)
  stage(Bbase + 64, 65536 + 32768);         // B0(1)
  asm volatile("s_waitcnt vmcnt(4)" ::: "memory");
  __builtin_amdgcn_s_barrier();

  for (int kt = 0; kt < NT; ++kt) {
    const int cur = (kt & 1) << 16, nxt = ((kt + 1) & 1) << 16;
    const _Float16* Akt1 = Abase + (kt + 1) * GBK;
    const _Float16* Bkt1 = Bbase + (kt + 1) * GBK;
    const _Float16* Akt2 = Abase + (kt + 2) * GBK;
    const _Float16* Bkt2 = Bbase + (kt + 2) * GBK;

    half8 a[4][2], b0[2][2], b1[2][2];

#pragma unroll
    for (int mi = 0; mi < 4; ++mi)
#pragma unroll
      for (int ks = 0; ks < 2; ++ks)
        a[mi][ks] = *(const half8*)(lds + cur + (aO[mi] ^ (ks << 6)));
#pragma unroll
    for (int ni = 0; ni < 2; ++ni)
#pragma unroll
      for (int ks = 0; ks < 2; ++ks) {
        b0[ni][ks] = *(const half8*)(lds + cur + 32768 + (bO[ni] ^ (ks << 6)));
        b1[ni][ks] = *(const half8*)(lds + cur + 49152 + (bO[ni] ^ (ks << 6)));
      }
    if (kt + 1 < NT) stage(Bkt1 + 128 * Kdim, nxt + 49152);  // s0: B1(kt+1)

    __builtin_amdgcn_s_setprio(1);
#pragma unroll
    for (int ks = 0; ks < 2; ++ks)
#pragma unroll
      for (int mi = 0; mi < 4; ++mi)
#pragma unroll
        for (int ni = 0; ni < 2; ++ni)
          acc[mi][ni] = __builtin_amdgcn_mfma_f32_16x16x32_f16(
              a[mi][ks], b0[ni][ks], acc[mi][ni], 0, 0, 0);
    __builtin_amdgcn_s_setprio(0);
    if (kt + 1 < NT) stage(Akt1 + 128 * Kdim, nxt + 16384);  // s1: A1(kt+1)

    __builtin_amdgcn_s_setprio(1);
#pragma unroll
    for (int ks = 0; ks < 2; ++ks)
#pragma unroll
      for (int mi = 0; mi < 4; ++mi)
#pragma unroll
        for (int ni = 0; ni < 2; ++ni)
          acc[mi][2 + ni] = __builtin_amdgcn_mfma_f32_16x16x32_f16(
              a[mi][ks], b1[ni][ks], acc[mi][2 + ni], 0, 0, 0);
    __builtin_amdgcn_s_setprio(0);

    __builtin_amdgcn_s_barrier();

#pragma unroll
    for (int mi = 0; mi < 4; ++mi)
#pragma unroll
      for (int ks = 0; ks < 2; ++ks)
        a[mi][ks] = *(const half8*)(lds + cur + 16384 + (aO[mi] ^ (ks << 6)));
    if (kt + 2 < NT) stage(Akt2, cur + 0);  // s2: A0(kt+2)

    __builtin_amdgcn_s_setprio(1);
#pragma unroll
    for (int ks = 0; ks < 2; ++ks)
#pragma unroll
      for (int mi = 0; mi < 4; ++mi)
#pragma unroll
        for (int ni = 0; ni < 2; ++ni)
          acc[4 + mi][ni] = __builtin_amdgcn_mfma_f32_16x16x32_f16(
              a[mi][ks], b0[ni][ks], acc[4 + mi][ni], 0, 0, 0);
    __builtin_amdgcn_s_setprio(0);
    if (kt + 2 < NT) stage(Bkt2, cur + 32768);  // s3: B0(kt+2)

    __builtin_amdgcn_s_setprio(1);
#pragma unroll
    for (int ks = 0; ks < 2; ++ks)
#pragma unroll
      for (int mi = 0; mi < 4; ++mi)
#pragma unroll
        for (int ni = 0; ni < 2; ++ni)
          acc[4 + mi][2 + ni] = __builtin_amdgcn_mfma_f32_16x16x32_f16(
              a[mi][ks], b1[ni][ks], acc[4 + mi][2 + ni], 0, 0, 0);
    __builtin_amdgcn_s_setprio(0);

    if (kt < NT - 2) {
      asm volatile("s_waitcnt vmcnt(4)" ::: "memory");
      __builtin_amdgcn_s_barrier();
    } else if (kt == NT - 2) {
      asm volatile("s_waitcnt vmcnt(0)" ::: "memory");
      __builtin_amdgcn_s_barrier();
    }
  }

#pragma unroll
  for (int mf = 0; mf < 8; ++mf) {
    int row = m0 + ((mf >> 2) << 7) + wm * 64 + ((mf & 3) << 4) + (lq << 2);
#pragma unroll
    for (int nf = 0; nf < 4; ++nf) {
      int col = n0 + ((nf >> 1) << 7) + wn * 32 + ((nf & 1) << 4) + l15;
#pragma unroll
      for (int r = 0; r < 4; ++r)
        Cg[(size_t)(row + r) * Ndim + col] = (_Float16)acc[mf][nf][r];
    }
  }
}

// ---------------------------------------------------------------- K3: per-chunk scan + emit packed (f,v) fp16
// G: gates [M][3D] fp16. 256 threads x 4 d-channels. fv: [M][D][2] fp16.
__global__ __launch_bounds__(256) void scan1_k(const _Float16* __restrict__ G,
                                               _Float16* __restrict__ fv,
                                               float* __restrict__ Fc,
                                               float* __restrict__ Hc) {
  int d = threadIdx.x * 4;
  int c = blockIdx.y, b = blockIdx.z;
  int64_t m0 = (int64_t)(b * Ss + c * LCH);
  const _Float16* g = G + m0 * Ndim + d;
  _Float16* fvp = fv + (m0 * Dd + d) * 2;
  float h[4] = {0.f, 0.f, 0.f, 0.f};
  float F[4] = {1.f, 1.f, 1.f, 1.f};
#pragma unroll 4
  for (int s = 0; s < LCH; ++s) {
    half4v fg = *(const half4v*)(g);
    half4v ig = *(const half4v*)(g + Dd);
    half4v hg = *(const half4v*)(g + 2 * Dd);
    half8 o;
#pragma unroll
    for (int j = 0; j < 4; ++j) {
      float fw, v;
      gate_fv((float)fg[j], (float)ig[j], (float)hg[j], fw, v);
      _Float16 fh = (_Float16)fw, vh = (_Float16)v;
      o[2 * j] = fh;
      o[2 * j + 1] = vh;
      float fr = (float)fh, vr = (float)vh;  // rounded: consistent with replay
      h[j] = fmaf(fr, h[j], vr);
      F[j] *= fr;
    }
    *(half8*)fvp = o;
    g += Ndim;
    fvp += Dd * 2;
  }
  int co = (b * CH + c) * Dd + d;
  *(floatx4*)(Fc + co) = *(floatx4*)F;
  *(floatx4*)(Hc + co) = *(floatx4*)h;
}

// ---------------------------------------------------------------- K4: chunk-carry scan (tiny)
__global__ __launch_bounds__(256) void scan2_k(const float* __restrict__ Fc,
                                               const float* __restrict__ Hc,
                                               float* __restrict__ Carry) {
  int idx = blockIdx.x * 256 + threadIdx.x;  // 0..4095
  int b = idx >> 10, d = idx & (Dd - 1);
  float carry = 0.f;
#pragma unroll 8
  for (int c = 0; c < CH; ++c) {
    int co = (b * CH + c) * Dd + d;
    Carry[co] = carry;
    carry = fmaf(Fc[co], carry, Hc[co]);
  }
}

// ---------------------------------------------------------------- K5: replay from packed fv with carry, write fp32
__global__ __launch_bounds__(256) void scan3_k(const _Float16* __restrict__ fv,
                                               const float* __restrict__ Carry,
                                               float* __restrict__ Out) {
  int d = threadIdx.x * 4;
  int c = blockIdx.y, b = blockIdx.z;
  int64_t m0 = (int64_t)(b * Ss + c * LCH);
  const _Float16* fvp = fv + (m0 * Dd + d) * 2;
  float* o = Out + m0 * Dd + d;
  int co = (b * CH + c) * Dd + d;
  floatx4 hv = *(const floatx4*)(Carry + co);
  float h[4] = {hv[0], hv[1], hv[2], hv[3]};
#pragma unroll 4
  for (int s = 0; s < LCH; ++s) {
    half8 p = *(const half8*)fvp;
#pragma unroll
    for (int j = 0; j < 4; ++j)
      h[j] = fmaf((float)p[2 * j], h[j], (float)p[2 * j + 1]);
    *(floatx4*)o = *(floatx4*)h;
    fvp += Dd * 2;
    o += Dd;
  }
}

// ---------------------------------------------------------------- launch
extern "C" void kernel_launch(void* const* d_in, const int* in_sizes, int n_in,
                              void* d_out, int out_size, void* d_ws, size_t ws_size,
                              hipStream_t stream) {
  const float* x = (const float*)d_in[0];   // [B,S,D] fp32
  const float* W = (const float*)d_in[1];   // [D,3D] fp32
  float* out = (float*)d_out;               // [B,S,D] fp32

  char* ws = (char*)d_ws;
  size_t off = 0;
  auto alloc = [&](size_t bytes) {
    char* p = ws + off;
    off += (bytes + 255) & ~size_t(255);
    return p;
  };
  // long-lived
  _Float16* gates  = (_Float16*)alloc((size_t)Mdim * Ndim * 2);       // 96 MiB
  float* Fc        = (float*)alloc((size_t)Bb * CH * Dd * 4);         // 4 MiB
  float* Hc        = (float*)alloc((size_t)Bb * CH * Dd * 4);         // 4 MiB
  float* Carry     = (float*)alloc((size_t)Bb * CH * Dd * 4);         // 4 MiB
  // union region: {x16 32 MiB + w16t 6 MiB} (dead after gemm)  vs  {fv 64 MiB}
  char* uni        = alloc((size_t)Mdim * Dd * 2 * 2);                // 64 MiB
  _Float16* x16    = (_Float16*)uni;
  _Float16* w16t   = (_Float16*)(uni + (size_t)Mdim * Kdim * 2);
  _Float16* fv     = (_Float16*)uni;
  if (off > ws_size) return;  // workspace too small: fail cleanly

  cvt_x_k<<<2048, 256, 0, stream>>>(x, x16, Mdim * Kdim / 4);
  cvt_wT_k<<<dim3(Ndim / 32, Kdim / 32), 256, 0, stream>>>(W, w16t);
  gemm8_k<<<dim3((Mdim / GBM) * (Ndim / GBN)), 512, 131072, stream>>>(x16, w16t, gates);
  scan1_k<<<dim3(1, CH, Bb), 256, 0, stream>>>(gates, fv, Fc, Hc);
  scan2_k<<<(Bb * Dd) / 256, 256, 0, stream>>>(Fc, Hc, Carry);
  scan3_k<<<dim3(1, CH, Bb), 256, 0, stream>>>(fv, Carry, out);
}

// Round 8
// 192.853 us; speedup vs baseline: 4.1197x; 1.0223x over previous
//
#include <hip/hip_runtime.h>
#include <hip/hip_fp16.h>
#include <cstdint>

typedef _Float16 half8  __attribute__((ext_vector_type(8)));
typedef _Float16 half4v __attribute__((ext_vector_type(4)));
typedef float    floatx4 __attribute__((ext_vector_type(4)));

// problem dims (fixed by setup_inputs)
constexpr int Bb = 4, Ss = 4096, Dd = 1024;
constexpr int Mdim = Bb * Ss;          // 16384
constexpr int Ndim = 3 * Dd;           // 3072
constexpr int Kdim = Dd;               // 1024
constexpr int CH = 256, LCH = Ss / CH; // 256 chunks of 16 steps

// ---------------------------------------------------------------- utils
__device__ __forceinline__ void gload_lds16(const void* g, void* l) {
  __builtin_amdgcn_global_load_lds(
      (const __attribute__((address_space(1))) uint32_t*)g,
      (__attribute__((address_space(3))) uint32_t*)l, 16, 0, 0);
}

// gate math: fw = sig(f)/(sig(f)+sig(i)) = (1+e^-i)/(2+e^-f+e^-i)
//            iw = (1+e^-f)/(2+e^-f+e^-i);  v = iw * g~(h)
__device__ __forceinline__ void gate_fv(float fg, float ig, float hg,
                                        float& fw, float& v) {
  float ef = __expf(fminf(-fg, 40.f));
  float ei = __expf(fminf(-ig, 40.f));
  float r  = __builtin_amdgcn_rcpf(2.f + ef + ei);
  fw = (1.f + ei) * r;
  float iw = (1.f + ef) * r;
  float g  = hg >= 0.f ? hg + 0.5f
                       : __builtin_amdgcn_rcpf(1.f + __expf(fminf(-hg, 40.f)));
  v = iw * g;
}

// ---------------------------------------------------------------- K0: fused x->fp16 + W transpose->fp16
// blocks [0,2048): x cvt (grid-stride float4); blocks [2048,5120): W^T tiles.
__global__ __launch_bounds__(256) void cvt_k(const float* __restrict__ X,
                                             _Float16* __restrict__ X16,
                                             const float* __restrict__ W,
                                             _Float16* __restrict__ WT) {
  __shared__ float tile[32][33];
  int bid = blockIdx.x;
  if (bid < 2048) {
    const int n4 = Mdim * Kdim / 4;
    for (int i = bid * 256 + threadIdx.x; i < n4; i += 2048 * 256) {
      float4 v = ((const float4*)X)[i];
      half4v o = {(_Float16)v.x, (_Float16)v.y, (_Float16)v.z, (_Float16)v.w};
      ((half4v*)X16)[i] = o;
    }
  } else {
    int b2 = bid - 2048;
    int tx = threadIdx.x & 31, ty = threadIdx.x >> 5;  // 32 x 8
    int n0 = (b2 % 96) * 32, k0 = (b2 / 96) * 32;
#pragma unroll
    for (int j = 0; j < 4; ++j) {
      int k = ty + j * 8;
      tile[k][tx] = W[(int64_t)(k0 + k) * Ndim + n0 + tx];
    }
    __syncthreads();
#pragma unroll
    for (int j = 0; j < 4; ++j) {
      int nl = ty + j * 8;
      WT[(int64_t)(n0 + nl) * Kdim + k0 + tx] = (_Float16)tile[tx][nl];
    }
  }
}

// ---------------------------------------------------------------- K1: 256x256 GEMM, deep-prefetch 2-barrier/tile
// A: x16 [M][K]; BT: W16T [N][K]; C: gates16 [M][N]. All fp16.
// LDS per buffer (64 KiB): A-half0 | A-half1 | B-half0 | B-half1, each
// 128 rows x 64 cols fp16, row stride 128 B, XOR-swizzled 16B slots.
// B-halves are register-cached for the whole tile => LDS B0 dead after the
// head reads; mid-barrier moves to right-after-Q0 and s2/s3 issue early.
constexpr int GBM = 256, GBN = 256, GBK = 64;
constexpr int NT = Kdim / GBK;  // 16 K-tiles

__global__ __launch_bounds__(512, 2) void gemm8_k(const _Float16* __restrict__ A,
                                                  const _Float16* __restrict__ BT,
                                                  _Float16* __restrict__ Cg) {
  extern __shared__ char lds[];  // 131072 bytes
  const int tid = threadIdx.x;
  const int wid = tid >> 6, lane = tid & 63;
  const int wm = wid >> 2, wn = wid & 3;
  const int l15 = lane & 15, lq = lane >> 4;

  // XCD-aware swizzle (768 % 8 == 0 -> simple variant is bijective)
  int wg = blockIdx.x;
  wg = (wg & 7) * 96 + (wg >> 3);
  const int n0 = (wg % 12) * GBN;
  const int m0 = (wg / 12) * GBM;

  int aO[4], bO[2];
#pragma unroll
  for (int mi = 0; mi < 4; ++mi) {
    int r = wm * 64 + mi * 16 + l15;
    aO[mi] = r * 128 + ((lq ^ (r & 7)) << 4);
  }
#pragma unroll
  for (int ni = 0; ni < 2; ++ni) {
    int r = wn * 32 + ni * 16 + l15;
    bO[ni] = r * 128 + ((lq ^ (r & 7)) << 4);
  }

  const int srr = (wid << 3) + (lane >> 3);
  const int ss = lane & 7;
  const _Float16* Abase = A + (size_t)m0 * Kdim;
  const _Float16* Bbase = BT + (size_t)n0 * Kdim;

  auto stage = [&](const _Float16* gsrc, int ldsHalfBase) {
#pragma unroll
    for (int round = 0; round < 2; ++round) {
      int r = (round << 6) + srr;
      int c = ss ^ (r & 7);
      gload_lds16(gsrc + (size_t)r * Kdim + (c << 3),
                  lds + ldsHalfBase + (round << 13) + (wid << 10));
    }
  };

  floatx4 acc[8][4] = {};

  // prologue: tile0 all 4 halves + tile1 A0,B0  (12 loads/lane-slice)
  stage(Abase, 0);                          // A0(0)
  stage(Bbase, 32768);                      // B0(0)
  stage(Bbase + 128 * Kdim, 49152);         // B1(0)
  stage(Abase + 128 * Kdim, 16384);         // A1(0)
  stage(Abase + 64, 65536);                 // A0(1)
  stage(Bbase + 64, 65536 + 32768);         // B0(1)
  asm volatile("s_waitcnt vmcnt(4)" ::: "memory");  // tile0 fully landed
  __builtin_amdgcn_s_barrier();

  for (int kt = 0; kt < NT; ++kt) {
    const int cur = (kt & 1) << 16, nxt = ((kt + 1) & 1) << 16;
    const _Float16* Akt1 = Abase + (kt + 1) * GBK;
    const _Float16* Bkt1 = Bbase + (kt + 1) * GBK;
    const _Float16* Akt2 = Abase + (kt + 2) * GBK;
    const _Float16* Bkt2 = Bbase + (kt + 2) * GBK;

    half8 a[4][2], b0[2][2], b1[2][2];

    // ---- head reads: A0(8), B0(4), B1(4); B halves reg-cached for the tile
#pragma unroll
    for (int mi = 0; mi < 4; ++mi)
#pragma unroll
      for (int ks = 0; ks < 2; ++ks)
        a[mi][ks] = *(const half8*)(lds + cur + (aO[mi] ^ (ks << 6)));
#pragma unroll
    for (int ni = 0; ni < 2; ++ni)
#pragma unroll
      for (int ks = 0; ks < 2; ++ks) {
        b0[ni][ks] = *(const half8*)(lds + cur + 32768 + (bO[ni] ^ (ks << 6)));
        b1[ni][ks] = *(const half8*)(lds + cur + 49152 + (bO[ni] ^ (ks << 6)));
      }
    if (kt + 1 < NT) stage(Bkt1 + 128 * Kdim, nxt + 49152);  // s0: B1(kt+1)

    // ---- Q0 = A0 x B0
    __builtin_amdgcn_s_setprio(1);
#pragma unroll
    for (int ks = 0; ks < 2; ++ks)
#pragma unroll
      for (int mi = 0; mi < 4; ++mi)
#pragma unroll
        for (int ni = 0; ni < 2; ++ni)
          acc[mi][ni] = __builtin_amdgcn_mfma_f32_16x16x32_f16(
              a[mi][ks], b0[ni][ks], acc[mi][ni], 0, 0, 0);
    __builtin_amdgcn_s_setprio(0);
    if (kt + 1 < NT) stage(Akt1 + 128 * Kdim, nxt + 16384);  // s1: A1(kt+1)

    // mid barrier: by now every wave's A0/B0 LDS reads are complete (consumed
    // by its Q0); only B1 reads may be in flight and s2/s3 don't touch B1.
    __builtin_amdgcn_s_barrier();
    if (kt + 2 < NT) {
      stage(Akt2, cur + 0);       // s2: A0(kt+2) over dead cur-A0
      stage(Bkt2, cur + 32768);   // s3: B0(kt+2) over dead cur-B0
    }

    // ---- Q1 = A0 x B1
    __builtin_amdgcn_s_setprio(1);
#pragma unroll
    for (int ks = 0; ks < 2; ++ks)
#pragma unroll
      for (int mi = 0; mi < 4; ++mi)
#pragma unroll
        for (int ni = 0; ni < 2; ++ni)
          acc[mi][2 + ni] = __builtin_amdgcn_mfma_f32_16x16x32_f16(
              a[mi][ks], b1[ni][ks], acc[mi][2 + ni], 0, 0, 0);
    __builtin_amdgcn_s_setprio(0);

    // ---- reload a <- A1 (A0 regs dead after Q1)
#pragma unroll
    for (int mi = 0; mi < 4; ++mi)
#pragma unroll
      for (int ks = 0; ks < 2; ++ks)
        a[mi][ks] = *(const half8*)(lds + cur + 16384 + (aO[mi] ^ (ks << 6)));

    // ---- Q2 + Q3 = A1 x {B0,B1} — contiguous 32-MFMA run
    __builtin_amdgcn_s_setprio(1);
#pragma unroll
    for (int ks = 0; ks < 2; ++ks)
#pragma unroll
      for (int mi = 0; mi < 4; ++mi)
#pragma unroll
        for (int ni = 0; ni < 2; ++ni)
          acc[4 + mi][ni] = __builtin_amdgcn_mfma_f32_16x16x32_f16(
              a[mi][ks], b0[ni][ks], acc[4 + mi][ni], 0, 0, 0);
#pragma unroll
    for (int ks = 0; ks < 2; ++ks)
#pragma unroll
      for (int mi = 0; mi < 4; ++mi)
#pragma unroll
        for (int ni = 0; ni < 2; ++ni)
          acc[4 + mi][2 + ni] = __builtin_amdgcn_mfma_f32_16x16x32_f16(
              a[mi][ks], b1[ni][ks], acc[4 + mi][2 + ni], 0, 0, 0);
    __builtin_amdgcn_s_setprio(0);

    // K-tile boundary: counted vmcnt (never 0 mid-loop), then barrier
    if (kt < NT - 2) {
      asm volatile("s_waitcnt vmcnt(4)" ::: "memory");
      __builtin_amdgcn_s_barrier();
    } else if (kt == NT - 2) {
      asm volatile("s_waitcnt vmcnt(0)" ::: "memory");  // drain: no stages left
      __builtin_amdgcn_s_barrier();
    }
  }

  // epilogue: D layout col=l15, row=lq*4+r
#pragma unroll
  for (int mf = 0; mf < 8; ++mf) {
    int row = m0 + ((mf >> 2) << 7) + wm * 64 + ((mf & 3) << 4) + (lq << 2);
#pragma unroll
    for (int nf = 0; nf < 4; ++nf) {
      int col = n0 + ((nf >> 1) << 7) + wn * 32 + ((nf & 1) << 4) + l15;
#pragma unroll
      for (int r = 0; r < 4; ++r)
        Cg[(size_t)(row + r) * Ndim + col] = (_Float16)acc[mf][nf][r];
    }
  }
}

// ---------------------------------------------------------------- K3: per-chunk scan (recomputes gates inline)
// G: gates [M][3D] fp16. 256 threads x 4 d-channels (half4 loads).
__global__ __launch_bounds__(256) void scan1_k(const _Float16* __restrict__ G,
                                               float* __restrict__ Fc,
                                               float* __restrict__ Hc) {
  int d = threadIdx.x * 4;
  int c = blockIdx.y, b = blockIdx.z;
  const _Float16* g = G + (int64_t)(b * Ss + c * LCH) * Ndim + d;
  float h[4] = {0.f, 0.f, 0.f, 0.f};
  float F[4] = {1.f, 1.f, 1.f, 1.f};
#pragma unroll 4
  for (int s = 0; s < LCH; ++s) {
    half4v fg = *(const half4v*)(g);
    half4v ig = *(const half4v*)(g + Dd);
    half4v hg = *(const half4v*)(g + 2 * Dd);
#pragma unroll
    for (int j = 0; j < 4; ++j) {
      float fw, v;
      gate_fv((float)fg[j], (float)ig[j], (float)hg[j], fw, v);
      h[j] = fmaf(fw, h[j], v);
      F[j] *= fw;
    }
    g += Ndim;
  }
  int co = (b * CH + c) * Dd + d;
  *(floatx4*)(Fc + co) = *(floatx4*)F;
  *(floatx4*)(Hc + co) = *(floatx4*)h;
}

// ---------------------------------------------------------------- K4: chunk-carry scan (tiny)
__global__ __launch_bounds__(256) void scan2_k(const float* __restrict__ Fc,
                                               const float* __restrict__ Hc,
                                               float* __restrict__ Carry) {
  int idx = blockIdx.x * 256 + threadIdx.x;  // 0..4095
  int b = idx >> 10, d = idx & (Dd - 1);
  float carry = 0.f;
#pragma unroll 8
  for (int c = 0; c < CH; ++c) {
    int co = (b * CH + c) * Dd + d;
    Carry[co] = carry;
    carry = fmaf(Fc[co], carry, Hc[co]);
  }
}

// ---------------------------------------------------------------- K5: replay with carry, write fp32 out
__global__ __launch_bounds__(256) void scan3_k(const _Float16* __restrict__ G,
                                               const float* __restrict__ Carry,
                                               float* __restrict__ Out) {
  int d = threadIdx.x * 4;
  int c = blockIdx.y, b = blockIdx.z;
  int64_t row0 = (int64_t)(b * Ss + c * LCH);
  const _Float16* g = G + row0 * Ndim + d;
  float* o = Out + row0 * Dd + d;
  int co = (b * CH + c) * Dd + d;
  floatx4 hv = *(const floatx4*)(Carry + co);
  float h[4] = {hv[0], hv[1], hv[2], hv[3]};
#pragma unroll 4
  for (int s = 0; s < LCH; ++s) {
    half4v fg = *(const half4v*)(g);
    half4v ig = *(const half4v*)(g + Dd);
    half4v hg = *(const half4v*)(g + 2 * Dd);
#pragma unroll
    for (int j = 0; j < 4; ++j) {
      float fw, v;
      gate_fv((float)fg[j], (float)ig[j], (float)hg[j], fw, v);
      h[j] = fmaf(fw, h[j], v);
    }
    *(floatx4*)o = *(floatx4*)h;
    g += Ndim;
    o += Dd;
  }
}

// ---------------------------------------------------------------- launch
extern "C" void kernel_launch(void* const* d_in, const int* in_sizes, int n_in,
                              void* d_out, int out_size, void* d_ws, size_t ws_size,
                              hipStream_t stream) {
  const float* x = (const float*)d_in[0];   // [B,S,D] fp32
  const float* W = (const float*)d_in[1];   // [D,3D] fp32
  float* out = (float*)d_out;               // [B,S,D] fp32

  char* ws = (char*)d_ws;
  size_t off = 0;
  auto alloc = [&](size_t bytes) {
    char* p = ws + off;
    off += (bytes + 255) & ~size_t(255);
    return p;
  };
  _Float16* gates  = (_Float16*)alloc((size_t)Mdim * Ndim * 2);       // 96 MiB
  float* Fc        = (float*)alloc((size_t)Bb * CH * Dd * 4);         // 4 MiB
  float* Hc        = (float*)alloc((size_t)Bb * CH * Dd * 4);
  float* Carry     = (float*)alloc((size_t)Bb * CH * Dd * 4);
  _Float16* x16    = (_Float16*)alloc((size_t)Mdim * Kdim * 2);       // 32 MiB
  _Float16* w16t   = (_Float16*)alloc((size_t)Ndim * Kdim * 2);       // 6 MiB
  if (off > ws_size) return;  // workspace too small: fail cleanly

  cvt_k<<<5120, 256, 0, stream>>>(x, x16, W, w16t);
  gemm8_k<<<dim3((Mdim / GBM) * (Ndim / GBN)), 512, 131072, stream>>>(x16, w16t, gates);
  scan1_k<<<dim3(1, CH, Bb), 256, 0, stream>>>(gates, Fc, Hc);
  scan2_k<<<(Bb * Dd) / 256, 256, 0, stream>>>(Fc, Hc, Carry);
  scan3_k<<<dim3(1, CH, Bb), 256, 0, stream>>>(gates, Carry, out);
}

// Round 9
// 183.272 us; speedup vs baseline: 4.3350x; 1.0523x over previous
//
#include <hip/hip_runtime.h>
#include <hip/hip_fp16.h>
#include <cstdint>

typedef _Float16 half8  __attribute__((ext_vector_type(8)));
typedef _Float16 half4v __attribute__((ext_vector_type(4)));
typedef _Float16 half2v __attribute__((ext_vector_type(2)));
typedef float    floatx4 __attribute__((ext_vector_type(4)));

// problem dims (fixed by setup_inputs)
constexpr int Bb = 4, Ss = 4096, Dd = 1024;
constexpr int Mdim = Bb * Ss;          // 16384
constexpr int Ndim = 3 * Dd;           // 3072
constexpr int Kdim = Dd;               // 1024
constexpr int CH = 256, LCH = Ss / CH; // 256 chunks of 16 steps

// ---------------------------------------------------------------- utils
__device__ __forceinline__ void gload_lds16(const void* g, void* l) {
  __builtin_amdgcn_global_load_lds(
      (const __attribute__((address_space(1))) uint32_t*)g,
      (__attribute__((address_space(3))) uint32_t*)l, 16, 0, 0);
}

// gate math: fw = sig(f)/(sig(f)+sig(i)) = (1+e^-i)/(2+e^-f+e^-i)
//            iw = (1+e^-f)/(2+e^-f+e^-i);  v = iw * g~(h)
__device__ __forceinline__ void gate_fv(float fg, float ig, float hg,
                                        float& fw, float& v) {
  float ef = __expf(fminf(-fg, 40.f));
  float ei = __expf(fminf(-ig, 40.f));
  float r  = __builtin_amdgcn_rcpf(2.f + ef + ei);
  fw = (1.f + ei) * r;
  float iw = (1.f + ef) * r;
  float g  = hg >= 0.f ? hg + 0.5f
                       : __builtin_amdgcn_rcpf(1.f + __expf(fminf(-hg, 40.f)));
  v = iw * g;
}

// ---------------------------------------------------------------- K0: fused x->fp16 + W transpose->fp16 (permuted)
// blocks [0,2048): x cvt; blocks [2048,5120): W^T tiles with row permutation
// p(n) = (d>>6)*192 + g*64 + (d&63), g=n/1024, d=n%1024 -> each GEMM n-block
// gets contiguous rows [j*192, j*192+192) = {f,i,h} for d in [j*64,(j+1)*64).
__global__ __launch_bounds__(256) void cvt_k(const float* __restrict__ X,
                                             _Float16* __restrict__ X16,
                                             const float* __restrict__ W,
                                             _Float16* __restrict__ WT) {
  __shared__ float tile[32][33];
  int bid = blockIdx.x;
  if (bid < 2048) {
    const int n4 = Mdim * Kdim / 4;
    for (int i = bid * 256 + threadIdx.x; i < n4; i += 2048 * 256) {
      float4 v = ((const float4*)X)[i];
      half4v o = {(_Float16)v.x, (_Float16)v.y, (_Float16)v.z, (_Float16)v.w};
      ((half4v*)X16)[i] = o;
    }
  } else {
    int b2 = bid - 2048;
    int tx = threadIdx.x & 31, ty = threadIdx.x >> 5;  // 32 x 8
    int n0 = (b2 % 96) * 32, k0 = (b2 / 96) * 32;
#pragma unroll
    for (int j = 0; j < 4; ++j) {
      int k = ty + j * 8;
      tile[k][tx] = W[(int64_t)(k0 + k) * Ndim + n0 + tx];
    }
    __syncthreads();
#pragma unroll
    for (int j = 0; j < 4; ++j) {
      int nl = ty + j * 8;
      int n = n0 + nl;
      int g = n >> 10, d = n & 1023;
      int p = (d >> 6) * 192 + g * 64 + (d & 63);
      WT[(int64_t)p * Kdim + k0 + tx] = (_Float16)tile[tx][nl];
    }
  }
}

// ---------------------------------------------------------------- K1: 256x192 GEMM + fused gate epilogue -> fv fp16
// A: x16 [M][K]; BT: permuted W^T [192*16][K]; out: fv [M][D][2] fp16.
// LDS per buffer (57344 B): A0 @0 | A1 @16384 | B @32768 (192 rows x 128 B),
// XOR-swizzled 16B slots; double buffer at stride 57344 (total 114688).
constexpr int GBM = 256, GBN = 192, GBK = 64;
constexpr int NT = Kdim / GBK;  // 16 K-tiles
constexpr int LBUF = 57344;

__global__ __launch_bounds__(512, 2) void gemm8_k(const _Float16* __restrict__ A,
                                                  const _Float16* __restrict__ BT,
                                                  _Float16* __restrict__ fv) {
  extern __shared__ char lds[];  // 114688 bytes
  const int tid = threadIdx.x;
  const int wid = tid >> 6, lane = tid & 63;
  const int wm = wid >> 2, wn = wid & 3;
  const int l15 = lane & 15, lq = lane >> 4;

  // XCD-aware swizzle (1024 % 8 == 0 -> bijective)
  int wg = blockIdx.x;
  wg = (wg & 7) * 128 + (wg >> 3);
  const int m0 = (wg >> 4) * GBM;       // 64 m-panels
  const int d0 = (wg & 15) * 64;        // 16 d-panels

  // LDS read byte-offsets (ks=0); ks=1 = offset ^ 64 (XOR-swizzle property)
  int aO[4];
#pragma unroll
  for (int mi = 0; mi < 4; ++mi) {
    int r = wm * 64 + mi * 16 + l15;
    aO[mi] = r * 128 + ((lq ^ (r & 7)) << 4);
  }
  const int rB = wn * 16 + l15;  // same local row for all 3 gates
  const int bO = rB * 128 + ((lq ^ (rB & 7)) << 4);

  // staging: thread -> (row srr + 64*round, slot ss); dest linear,
  // source column pre-inverse-swizzled (rule #21)
  const int srr = (wid << 3) + (lane >> 3);
  const int ss = lane & 7;
  const _Float16* Abase = A + (size_t)m0 * Kdim;
  const _Float16* Bbase = BT + (size_t)(wg & 15) * 192 * Kdim;

  auto stage = [&](const _Float16* gsrc, int ldsBase, int nr) {
#pragma unroll
    for (int round = 0; round < 3; ++round) {
      if (round >= nr) break;
      int r = (round << 6) + srr;
      int c = ss ^ (r & 7);
      gload_lds16(gsrc + (size_t)r * Kdim + (c << 3),
                  lds + ldsBase + (round << 13) + (wid << 10));
    }
  };

  floatx4 acc[8][3] = {};

  // prologue: tile0 {A0,B,A1} + tile1 {A0,B}  (12 loads/lane-slice)
  stage(Abase, 0, 2);                          // A0(0) [2]
  stage(Bbase, 32768, 3);                      // B(0)  [3]
  stage(Abase + 128 * Kdim, 16384, 2);         // A1(0) [2]
  stage(Abase + 64, LBUF, 2);                  // A0(1) [2]
  stage(Bbase + 64, LBUF + 32768, 3);          // B(1)  [3]
  asm volatile("s_waitcnt vmcnt(5)" ::: "memory");  // tile0 fully landed
  __builtin_amdgcn_s_barrier();

  for (int kt = 0; kt < NT; ++kt) {
    const int cur = (kt & 1) * LBUF, nxt = ((kt + 1) & 1) * LBUF;
    const _Float16* Akt1 = Abase + (kt + 1) * GBK;
    const _Float16* Akt2 = Abase + (kt + 2) * GBK;
    const _Float16* Bkt2 = Bbase + (kt + 2) * GBK;

    half8 a[4][2], b[3][2];

    // ---- head reads: A0(8 b128) + B(6 b128); B reg-cached for whole tile
#pragma unroll
    for (int mi = 0; mi < 4; ++mi)
#pragma unroll
      for (int ks = 0; ks < 2; ++ks)
        a[mi][ks] = *(const half8*)(lds + cur + (aO[mi] ^ (ks << 6)));
#pragma unroll
    for (int g = 0; g < 3; ++g)
#pragma unroll
      for (int ks = 0; ks < 2; ++ks)
        b[g][ks] = *(const half8*)(lds + cur + 32768 + (g << 13) + (bO ^ (ks << 6)));
    if (kt + 1 < NT) stage(Akt1 + 128 * Kdim, nxt + 16384, 2);  // s0: A1(kt+1)

    // ---- Q0 = A0 x B (24 MFMA)
    __builtin_amdgcn_s_setprio(1);
#pragma unroll
    for (int ks = 0; ks < 2; ++ks)
#pragma unroll
      for (int mi = 0; mi < 4; ++mi)
#pragma unroll
        for (int g = 0; g < 3; ++g)
          acc[mi][g] = __builtin_amdgcn_mfma_f32_16x16x32_f16(
              a[mi][ks], b[g][ks], acc[mi][g], 0, 0, 0);
    __builtin_amdgcn_s_setprio(0);

    // mid barrier: all waves' A0/B head reads complete (consumed by Q0)
    __builtin_amdgcn_s_barrier();

    // ---- A1 reads (reuse a[] regs), then restage dead cur regions
#pragma unroll
    for (int mi = 0; mi < 4; ++mi)
#pragma unroll
      for (int ks = 0; ks < 2; ++ks)
        a[mi][ks] = *(const half8*)(lds + cur + 16384 + (aO[mi] ^ (ks << 6)));
    if (kt + 2 < NT) {
      stage(Akt2, cur, 2);            // s1a: A0(kt+2) over dead cur-A0
      stage(Bkt2, cur + 32768, 3);    // s1b: B(kt+2)  over dead cur-B
    }

    // ---- Q1 = A1 x B (24 MFMA)
    __builtin_amdgcn_s_setprio(1);
#pragma unroll
    for (int ks = 0; ks < 2; ++ks)
#pragma unroll
      for (int mi = 0; mi < 4; ++mi)
#pragma unroll
        for (int g = 0; g < 3; ++g)
          acc[4 + mi][g] = __builtin_amdgcn_mfma_f32_16x16x32_f16(
              a[mi][ks], b[g][ks], acc[4 + mi][g], 0, 0, 0);
    __builtin_amdgcn_s_setprio(0);

    // K-tile boundary: counted vmcnt (never 0 mid-loop), then barrier
    if (kt < NT - 2) {
      asm volatile("s_waitcnt vmcnt(5)" ::: "memory");
      __builtin_amdgcn_s_barrier();
    } else if (kt == NT - 2) {
      asm volatile("s_waitcnt vmcnt(0)" ::: "memory");  // drain: no stages left
      __builtin_amdgcn_s_barrier();
    }
  }

  // epilogue: D layout col=l15, row=lq*4+r. Lane holds f,i,h for the SAME
  // 16 d-channels in acc[.][0..2] -> gate_fv on fp32, write packed half2.
  const int dcol = d0 + wn * 16 + l15;
#pragma unroll
  for (int hf = 0; hf < 2; ++hf)
#pragma unroll
    for (int mf = 0; mf < 4; ++mf) {
      int row = m0 + hf * 128 + wm * 64 + mf * 16 + (lq << 2);
#pragma unroll
      for (int r = 0; r < 4; ++r) {
        float fw, v;
        gate_fv(acc[hf * 4 + mf][0][r], acc[hf * 4 + mf][1][r],
                acc[hf * 4 + mf][2][r], fw, v);
        half2v o = {(_Float16)fw, (_Float16)v};
        *(half2v*)(fv + ((size_t)(row + r) * Dd + dcol) * 2) = o;
      }
    }
}

// ---------------------------------------------------------------- K3: per-chunk scan over packed fv (pure stream)
__global__ __launch_bounds__(256) void scan1_k(const _Float16* __restrict__ fv,
                                               float* __restrict__ Fc,
                                               float* __restrict__ Hc) {
  int d = threadIdx.x * 4;
  int c = blockIdx.y, b = blockIdx.z;
  const _Float16* p = fv + ((int64_t)(b * Ss + c * LCH) * Dd + d) * 2;
  float h[4] = {0.f, 0.f, 0.f, 0.f};
  float F[4] = {1.f, 1.f, 1.f, 1.f};
#pragma unroll 4
  for (int s = 0; s < LCH; ++s) {
    half8 q = *(const half8*)p;  // f0,v0,f1,v1,f2,v2,f3,v3
#pragma unroll
    for (int j = 0; j < 4; ++j) {
      float fr = (float)q[2 * j], vr = (float)q[2 * j + 1];
      h[j] = fmaf(fr, h[j], vr);
      F[j] *= fr;
    }
    p += Dd * 2;
  }
  int co = (b * CH + c) * Dd + d;
  *(floatx4*)(Fc + co) = *(floatx4*)F;
  *(floatx4*)(Hc + co) = *(floatx4*)h;
}

// ---------------------------------------------------------------- K4: chunk-carry scan (tiny)
__global__ __launch_bounds__(256) void scan2_k(const float* __restrict__ Fc,
                                               const float* __restrict__ Hc,
                                               float* __restrict__ Carry) {
  int idx = blockIdx.x * 256 + threadIdx.x;  // 0..4095
  int b = idx >> 10, d = idx & (Dd - 1);
  float carry = 0.f;
#pragma unroll 8
  for (int c = 0; c < CH; ++c) {
    int co = (b * CH + c) * Dd + d;
    Carry[co] = carry;
    carry = fmaf(Fc[co], carry, Hc[co]);
  }
}

// ---------------------------------------------------------------- K5: replay from packed fv with carry, write fp32
__global__ __launch_bounds__(256) void scan3_k(const _Float16* __restrict__ fv,
                                               const float* __restrict__ Carry,
                                               float* __restrict__ Out) {
  int d = threadIdx.x * 4;
  int c = blockIdx.y, b = blockIdx.z;
  int64_t m0 = (int64_t)(b * Ss + c * LCH);
  const _Float16* p = fv + (m0 * Dd + d) * 2;
  float* o = Out + m0 * Dd + d;
  int co = (b * CH + c) * Dd + d;
  floatx4 hv = *(const floatx4*)(Carry + co);
  float h[4] = {hv[0], hv[1], hv[2], hv[3]};
#pragma unroll 4
  for (int s = 0; s < LCH; ++s) {
    half8 q = *(const half8*)p;
#pragma unroll
    for (int j = 0; j < 4; ++j)
      h[j] = fmaf((float)q[2 * j], h[j], (float)q[2 * j + 1]);
    *(floatx4*)o = *(floatx4*)h;
    p += Dd * 2;
    o += Dd;
  }
}

// ---------------------------------------------------------------- launch
extern "C" void kernel_launch(void* const* d_in, const int* in_sizes, int n_in,
                              void* d_out, int out_size, void* d_ws, size_t ws_size,
                              hipStream_t stream) {
  const float* x = (const float*)d_in[0];   // [B,S,D] fp32
  const float* W = (const float*)d_in[1];   // [D,3D] fp32
  float* out = (float*)d_out;               // [B,S,D] fp32

  char* ws = (char*)d_ws;
  size_t off = 0;
  auto alloc = [&](size_t bytes) {
    char* p = ws + off;
    off += (bytes + 255) & ~size_t(255);
    return p;
  };
  _Float16* fv     = (_Float16*)alloc((size_t)Mdim * Dd * 2 * 2);     // 64 MiB
  float* Fc        = (float*)alloc((size_t)Bb * CH * Dd * 4);         // 4 MiB
  float* Hc        = (float*)alloc((size_t)Bb * CH * Dd * 4);
  float* Carry     = (float*)alloc((size_t)Bb * CH * Dd * 4);
  _Float16* x16    = (_Float16*)alloc((size_t)Mdim * Kdim * 2);       // 32 MiB
  _Float16* w16t   = (_Float16*)alloc((size_t)Ndim * Kdim * 2);       // 6 MiB
  if (off > ws_size) return;  // workspace too small: fail cleanly

  cvt_k<<<5120, 256, 0, stream>>>(x, x16, W, w16t);
  gemm8_k<<<dim3((Mdim / GBM) * (Dd / 64)), 512, 114688, stream>>>(x16, w16t, fv);
  scan1_k<<<dim3(1, CH, Bb), 256, 0, stream>>>(fv, Fc, Hc);
  scan2_k<<<(Bb * Dd) / 256, 256, 0, stream>>>(Fc, Hc, Carry);
  scan3_k<<<dim3(1, CH, Bb), 256, 0, stream>>>(fv, Carry, out);
}